// Round 6
// baseline (1176.513 us; speedup 1.0000x reference)
//
#include <hip/hip_runtime.h>
#include <math.h>
#include <stdint.h>

#define N_NODE 1024
#define NC 128            // b*d = 64*2
#define T_ALL 12
#define T1 11
#define NP 24             // period / number of graphs
#define NN (N_NODE*N_NODE)   // 1048576
#define HJ 72             // 3*H
#define HH 24             // H

// ---- workspace layout (float offsets) ----
#define WS_SC     0                                   // 12*1024*128 = 1572864
#define WS_COV    (WS_SC + T_ALL*N_NODE*NC)           // + 1048576 -> 2621440
#define WS_MPART  (WS_COV + NN)                       // + 2112    -> 2623552
#define WS_IDX    (WS_MPART + T1*NP*8)                // + 16      -> 2623568
#define WS_PROJ   (WS_IDX + 16)                       // + 25*72*128 = 230400
#define WS_GI     (WS_PROJ + 25*HJ*128)               // + 864     -> 2854832
#define WS_BASE_FLOATS (WS_GI + HJ*T_ALL)             // = 2854832... (see below)

// byte offsets for fp16 tile arrays (16B aligned: 2854832*4 % 16 == 0)
#define AB_BASE_BYTES ((size_t)(WS_GI + HJ*T_ALL) * 4)
#define AHI_BYTES ((size_t)24*1024*1024*2)            // 50331648 (A fp16)
#define BHI_BYTES ((size_t)11*32*4096*2)              // 2883584 (B fp16)
#define WS_NEED_BYTES (AB_BASE_BYTES + AHI_BYTES + BHI_BYTES)  // ~64.6MB

typedef __attribute__((ext_vector_type(8))) unsigned short ushort8v;
typedef __attribute__((ext_vector_type(8))) _Float16 half8v;
typedef __attribute__((ext_vector_type(4))) float f32x4;

// ---------------------------------------------------------------------------
__device__ __forceinline__ void gload16(const void* g, void* l) {
    __builtin_amdgcn_global_load_lds(
        (const __attribute__((address_space(1))) uint32_t*)g,
        (__attribute__((address_space(3))) uint32_t*)l, 16, 0, 0);
}

__device__ __forceinline__ unsigned short f16_bits(_Float16 h) {
    union { _Float16 f; unsigned short u; } cv; cv.f = h; return cv.u;
}

// ---------------------------------------------------------------------------
// L1 fused: build_sc (256 blocks) + cvt_A (6144 blocks)
// build_sc: sc[t][n][c] = inputs[b][n][t*2+dd], c=2b+dd; 8b x 32n tile.
// cvt_A: graphs -> tile-contiguous XOR-swizzled fp16.
__global__ __launch_bounds__(256) void k_pre1(const float* __restrict__ inp,
                                              const float* __restrict__ G,
                                              float* __restrict__ sc,
                                              unsigned short* __restrict__ Ahi) {
    __shared__ float ld[6432];   // addr(n,b,td) = n*201 + b*25 + td  (25.7KB)
    int tid = threadIdx.x;
    if (blockIdx.x < 256) {
        int b0 = (blockIdx.x & 7) * 8;
        int n0 = (blockIdx.x >> 3) * 32;
        for (int idx = tid; idx < 1536; idx += 256) {
            int bb = idx / 192;
            int rem = idx - bb * 192;
            int nn = rem / 6;
            int q  = rem - nn * 6;
            const float4 v = *(const float4*)(inp +
                ((size_t)(b0 + bb) * 1024 + (n0 + nn)) * 24 + q * 4);
            int base = nn * 201 + bb * 25 + q * 4;
            ld[base + 0] = v.x; ld[base + 1] = v.y;
            ld[base + 2] = v.z; ld[base + 3] = v.w;
        }
        __syncthreads();
        for (int idx = tid; idx < 6144; idx += 256) {
            int t = idx / 512;
            int rem = idx & 511;
            int nn = rem >> 4, cc = rem & 15;
            int bb = cc >> 1, dd = cc & 1;
            sc[(size_t)t * 131072 + (size_t)(n0 + nn) * 128 + b0 * 2 + cc] =
                ld[nn * 201 + bb * 25 + t * 2 + dd];
        }
    } else {
        int tile = blockIdx.x - 256;      // 0..6143 = (p*8+nt)*32+ks
        int ks = tile & 31;
        int pn = tile >> 5;
        int nt = pn & 7, p = pn >> 3;
        const float* Gt = G + (size_t)p * NN + (size_t)(nt * 128) * 1024 + ks * 32;
        size_t base = (size_t)tile * 4096;
#pragma unroll
        for (int g2 = 0; g2 < 2; ++g2) {
            int gid = tid * 2 + g2;   // 0..511
            int r = gid >> 2, gg = gid & 3;
            const float* src = Gt + (size_t)r * 1024 + gg * 8;
            ushort8v h;
#pragma unroll
            for (int j = 0; j < 8; ++j)
                h[j] = f16_bits((_Float16)src[j]);
            int offu = ((r * 64 + gg * 16) ^ ((r & 7) << 4)) >> 1;
            *(ushort8v*)(Ahi + base + offu) = h;
        }
    }
}

// ---------------------------------------------------------------------------
// L2 fused: cvt_B (352 blocks) + cov with inline row-means (256 blocks)
__global__ __launch_bounds__(256) void k_pre2(const float* __restrict__ sc,
                                              unsigned short* __restrict__ Bhi,
                                              float* __restrict__ cov) {
    __shared__ float shbuf[17152];   // cvt_B: s[32][129]; cov: Ai[0..8511], Bj[8512..]
    __shared__ float meanb[128];
    int tid = threadIdx.x;
    if (blockIdx.x < 352) {
        float (*s)[129] = (float(*)[129])shbuf;
        int tile = blockIdx.x;            // t*32+ks
        int ks = tile & 31;
        int t = tile >> 5;
        const float* S = sc + (size_t)t * (N_NODE * NC) + (size_t)ks * 32 * 128;
#pragma unroll
        for (int i = 0; i < 4; ++i) {
            int fi = tid + i * 256;
            int m = fi >> 5, c4 = fi & 31;
            float4 v = *(const float4*)(S + (size_t)m * 128 + c4 * 4);
            s[m][c4 * 4 + 0] = v.x;
            s[m][c4 * 4 + 1] = v.y;
            s[m][c4 * 4 + 2] = v.z;
            s[m][c4 * 4 + 3] = v.w;
        }
        __syncthreads();
        size_t base = (size_t)tile * 4096;
#pragma unroll
        for (int g2 = 0; g2 < 2; ++g2) {
            int gid = tid * 2 + g2;
            int c = gid >> 2, gg = gid & 3;
            ushort8v h;
#pragma unroll
            for (int j = 0; j < 8; ++j)
                h[j] = f16_bits((_Float16)s[gg * 8 + j][c]);
            int offu = ((c * 64 + gg * 16) ^ ((c & 7) << 4)) >> 1;
            *(ushort8v*)(Bhi + base + offu) = h;
        }
    } else {
        int cb = blockIdx.x - 352;        // 0..255
        int bi = cb >> 4, bj = cb & 15;
        int i0 = bi * 64, j0 = bj * 64;
        float* Ai = shbuf;
        float* Bj = shbuf + 8512;
        const float* L = sc + (size_t)11 * (N_NODE * NC);
        // stage raw
#pragma unroll
        for (int it = 0; it < 8; ++it) {
            int fi = tid + it * 256;
            int r = fi >> 5, q = fi & 31;
            float4 a4 = *(const float4*)(L + (size_t)(i0 + r) * 128 + q * 4);
            Ai[r * 133 + q * 4 + 0] = a4.x;
            Ai[r * 133 + q * 4 + 1] = a4.y;
            Ai[r * 133 + q * 4 + 2] = a4.z;
            Ai[r * 133 + q * 4 + 3] = a4.w;
            float4 b4 = *(const float4*)(L + (size_t)(j0 + r) * 128 + q * 4);
            Bj[r * 133 + q * 4 + 0] = b4.x;
            Bj[r * 133 + q * 4 + 1] = b4.y;
            Bj[r * 133 + q * 4 + 2] = b4.z;
            Bj[r * 133 + q * 4 + 3] = b4.w;
        }
        __syncthreads();
        // row means
        if (tid < 128) {
            int half = tid >> 6, row = tid & 63;
            const float* buf = (half ? Bj : Ai) + row * 133;
            float s = 0.f;
            for (int k = 0; k < 128; ++k) s += buf[k];
            meanb[tid] = s * (1.0f / 128.0f);
        }
        __syncthreads();
        // subtract in place
#pragma unroll
        for (int it = 0; it < 8; ++it) {
            int fi = tid + it * 256;
            int r = fi >> 5, q = fi & 31;
            float ma = meanb[r], mb = meanb[64 + r];
#pragma unroll
            for (int e = 0; e < 4; ++e) {
                Ai[r * 133 + q * 4 + e] -= ma;
                Bj[r * 133 + q * 4 + e] -= mb;
            }
        }
        __syncthreads();
        int ti = tid >> 4, tj = tid & 15;
        float acc[4][4];
#pragma unroll
        for (int a = 0; a < 4; ++a)
#pragma unroll
            for (int b = 0; b < 4; ++b) acc[a][b] = 0.f;
        for (int k = 0; k < 128; ++k) {
            float a[4], b[4];
#pragma unroll
            for (int rr = 0; rr < 4; ++rr) a[rr] = Ai[(ti * 4 + rr) * 133 + k];
#pragma unroll
            for (int cc = 0; cc < 4; ++cc) b[cc] = Bj[(tj * 4 + cc) * 133 + k];
#pragma unroll
            for (int rr = 0; rr < 4; ++rr)
#pragma unroll
                for (int cc = 0; cc < 4; ++cc)
                    acc[rr][cc] = fmaf(a[rr], b[cc], acc[rr][cc]);
        }
#pragma unroll
        for (int rr = 0; rr < 4; ++rr)
#pragma unroll
            for (int cc = 0; cc < 4; ++cc)
                cov[(size_t)(i0 + ti * 4 + rr) * 1024 + j0 + tj * 4 + cc] =
                    acc[rr][cc] * (1.0f / 127.0f);
    }
}

// ---------------------------------------------------------------------------
// proj body: proj[p][j] partials for ALL 24 graphs + cov (p=24).
// gid in [0,1152): kc = gid/9, jg = gid%9 (consecutive blocks share ctx chunk).
__device__ __forceinline__ void gi_proj_body(int gid, int tid,
                                             const float* __restrict__ Wih,
                                             const float* __restrict__ G,
                                             const float* __restrict__ cov,
                                             float* __restrict__ projpart) {
    int kc = gid / 9, jg = gid % 9;
    int lane = tid & 63, wv = tid >> 6;
    int j0 = jg * 8 + wv * 2;
    size_t kbase = (size_t)kc * 8192 + (size_t)lane * 4;
    const float* w0 = Wih + (size_t)j0 * NN;
    const float* w1 = w0 + NN;

    float acc0[25], acc1[25];
#pragma unroll
    for (int p = 0; p < 25; ++p) { acc0[p] = 0.f; acc1[p] = 0.f; }

    for (int s = 0; s < 32; ++s) {
        size_t k = kbase + (size_t)s * 256;
        float4 wa = *(const float4*)(w0 + k);
        float4 wb = *(const float4*)(w1 + k);
#pragma unroll
        for (int p = 0; p < 25; ++p) {
            const float* xp = (p < 24) ? (G + (size_t)p * NN + k) : (cov + k);
            float4 x = *(const float4*)xp;
            acc0[p] += wa.x * x.x + wa.y * x.y + wa.z * x.z + wa.w * x.w;
            acc1[p] += wb.x * x.x + wb.y * x.y + wb.z * x.z + wb.w * x.w;
        }
    }
#pragma unroll
    for (int p = 0; p < 25; ++p) {
        float v0 = acc0[p], v1 = acc1[p];
        for (int off = 32; off > 0; off >>= 1) {
            v0 += __shfl_xor(v0, off);
            v1 += __shfl_xor(v1, off);
        }
        if (lane == 0) {
            projpart[((size_t)p * HJ + j0) * 128 + kc] = v0;
            projpart[((size_t)p * HJ + j0 + 1) * 128 + kc] = v1;
        }
    }
}

// ---------------------------------------------------------------------------
// L3 fused: metrics MFMA (2112) + gi_proj (1152), Bresenham 11:6 per 17.
__global__ __launch_bounds__(256, 4) void k_main(
        const unsigned short* __restrict__ Ahi,
        const unsigned short* __restrict__ Bhi,
        const float* __restrict__ sc,
        const float* __restrict__ Wih,
        const float* __restrict__ G,
        const float* __restrict__ cov,
        float* __restrict__ mpart,
        float* __restrict__ projpart) {
    __shared__ unsigned short lds[2][2][4096];   // metrics only (32KB)
    __shared__ float red[256];

    int bid = blockIdx.x;            // 0..3263 (= 192*17)
    int grp = bid / 17, r = bid % 17;
    int gib = (r * 6) / 17;
    bool is_gi = ((r + 1) * 6) / 17 > gib;
    int tid = threadIdx.x;

    if (is_gi) {
        gi_proj_body(grp * 6 + gib, tid, Wih, G, cov, projpart);
        return;
    }

    int mt = grp * 11 + (r - gib);   // 0..2111
    int t = mt % 11;
    int pn = mt / 11;
    int nt = pn & 7, p = pn >> 3;

    int lane = tid & 63, wv = tid >> 6;
    int wr = wv >> 1, wc = wv & 1;
    int lr = lane & 15, lg = lane >> 4;

    const unsigned short* srcA = Ahi + (size_t)(p * 8 + nt) * 32 * 4096;
    const unsigned short* srcB = Bhi + (size_t)t * 32 * 4096;

    f32x4 acc[4][4];
#pragma unroll
    for (int m = 0; m < 4; ++m)
#pragma unroll
        for (int n = 0; n < 4; ++n)
            acc[m][n] = (f32x4){0.f, 0.f, 0.f, 0.f};

    int aoff[4], boff[4];
#pragma unroll
    for (int m = 0; m < 4; ++m) {
        int row = wr * 64 + m * 16 + lr;
        aoff[m] = (row * 64 + lg * 16) ^ ((row & 7) << 4);
    }
#pragma unroll
    for (int n = 0; n < 4; ++n) {
        int col = wc * 64 + n * 16 + lr;
        boff[n] = (col * 64 + lg * 16) ^ ((col & 7) << 4);
    }

    const char* LA = (const char*)&lds[0][0][0];
    const char* LB = (const char*)&lds[1][0][0];

    for (int ks2 = 0; ks2 < 16; ++ks2) {
        const unsigned short* sA = srcA + (size_t)ks2 * 8192;
        const unsigned short* sB = srcB + (size_t)ks2 * 8192;
#pragma unroll
        for (int i = 0; i < 8; ++i) {
            int c = wv + i * 4;               // 0..31
            int img = c >> 4, seg = c & 15;
            const unsigned short* sp = (img == 0 ? sA : sB) + seg * 512 + lane * 8;
            gload16(sp, &lds[img][seg >> 3][(seg & 7) * 512]);
        }
        __syncthreads();

        half8v bh[4][2];
#pragma unroll
        for (int n = 0; n < 4; ++n) {
            bh[n][0] = *(const half8v*)(LB + boff[n]);
            bh[n][1] = *(const half8v*)(LB + 8192 + boff[n]);
        }
#pragma unroll
        for (int m = 0; m < 4; ++m) {
            half8v ah0 = *(const half8v*)(LA + aoff[m]);
            half8v ah1 = *(const half8v*)(LA + 8192 + aoff[m]);
#pragma unroll
            for (int n = 0; n < 4; ++n) {
                acc[m][n] = __builtin_amdgcn_mfma_f32_16x16x32_f16(ah0, bh[n][0], acc[m][n], 0, 0, 0);
                acc[m][n] = __builtin_amdgcn_mfma_f32_16x16x32_f16(ah1, bh[n][1], acc[m][n], 0, 0, 0);
            }
        }
        __syncthreads();
    }

    const float* Tg = sc + (size_t)(t + 1) * (N_NODE * NC);
    int n0 = nt * 128;
    float part = 0.f;
#pragma unroll
    for (int m = 0; m < 4; ++m)
#pragma unroll
        for (int j = 0; j < 4; ++j) {
            int row = wr * 64 + m * 16 + lg * 4 + j;
            const float* Trow = Tg + (size_t)(n0 + row) * 128 + wc * 64 + lr;
#pragma unroll
            for (int n = 0; n < 4; ++n) {
                float tg = Trow[n * 16];
                if (tg != 0.0f) part += fabsf(acc[m][n][j] - tg);
            }
        }
    red[tid] = part;
    __syncthreads();
    for (int s = 128; s > 0; s >>= 1) {
        if (tid < s) red[tid] += red[tid + s];
        __syncthreads();
    }
    if (tid == 0) mpart[((size_t)t * NP + p) * 8 + nt] = red[0];
}

// standalone proj (fallback path only)
__global__ __launch_bounds__(256) void k_gi_proj(const float* __restrict__ Wih,
                                                 const float* __restrict__ G,
                                                 const float* __restrict__ cov,
                                                 float* __restrict__ projpart) {
    gi_proj_body(blockIdx.x, threadIdx.x, Wih, G, cov, projpart);
}

// ---------------------------------------------------------------------------
// fp32 metrics fallback (verified round 1) — only if ws_size too small
__global__ __launch_bounds__(256) void k_metrics(const float* __restrict__ G,
                                                 const float* __restrict__ sc,
                                                 float* __restrict__ mpart) {
    __shared__ float As[32 * 132];
    __shared__ float Bs[32 * 132];
    __shared__ float red[256];

    int nt = blockIdx.x, p = blockIdx.y, t = blockIdx.z;
    int tid = threadIdx.x;
    int tr = tid >> 4, tc = tid & 15;
    int n0 = nt * 128;

    const float* Gp = G + (size_t)p * NN + (size_t)n0 * 1024;
    const float* Xt = sc + (size_t)t * (N_NODE * NC);

    float acc[8][8];
#pragma unroll
    for (int a = 0; a < 8; ++a)
#pragma unroll
        for (int b = 0; b < 8; ++b) acc[a][b] = 0.f;

    for (int ko = 0; ko < 1024; ko += 32) {
#pragma unroll
        for (int it = 0; it < 4; ++it) {
            int fi = tid + it * 256;
            int r = fi >> 3, q = fi & 7;
            float4 g4 = *(const float4*)(Gp + (size_t)r * 1024 + ko + q * 4);
            As[(q * 4 + 0) * 132 + r] = g4.x;
            As[(q * 4 + 1) * 132 + r] = g4.y;
            As[(q * 4 + 2) * 132 + r] = g4.z;
            As[(q * 4 + 3) * 132 + r] = g4.w;
        }
#pragma unroll
        for (int it = 0; it < 4; ++it) {
            int fi = tid + it * 256;
            int kk = fi >> 5, cq = fi & 31;
            float4 x4 = *(const float4*)(Xt + (size_t)(ko + kk) * 128 + cq * 4);
            *(float4*)(&Bs[kk * 132 + cq * 4]) = x4;
        }
        __syncthreads();
#pragma unroll
        for (int kk = 0; kk < 32; ++kk) {
            float4 a0 = *(const float4*)(&As[kk * 132 + tr * 8]);
            float4 a1 = *(const float4*)(&As[kk * 132 + tr * 8 + 4]);
            float4 b0 = *(const float4*)(&Bs[kk * 132 + tc * 8]);
            float4 b1 = *(const float4*)(&Bs[kk * 132 + tc * 8 + 4]);
            float a[8] = {a0.x, a0.y, a0.z, a0.w, a1.x, a1.y, a1.z, a1.w};
            float b[8] = {b0.x, b0.y, b0.z, b0.w, b1.x, b1.y, b1.z, b1.w};
#pragma unroll
            for (int rr = 0; rr < 8; ++rr)
#pragma unroll
                for (int cc = 0; cc < 8; ++cc)
                    acc[rr][cc] = fmaf(a[rr], b[cc], acc[rr][cc]);
        }
        __syncthreads();
    }

    const float* Tg = sc + (size_t)(t + 1) * (N_NODE * NC);
    float part = 0.f;
#pragma unroll
    for (int rr = 0; rr < 8; ++rr) {
        int n = n0 + tr * 8 + rr;
#pragma unroll
        for (int cc = 0; cc < 8; ++cc) {
            int c = tc * 8 + cc;
            float tg = Tg[(size_t)n * 128 + c];
            if (tg != 0.0f) part += fabsf(acc[rr][cc] - tg);
        }
    }
    red[tid] = part;
    __syncthreads();
    for (int s = 128; s > 0; s >>= 1) {
        if (tid < s) red[tid] += red[tid + s];
        __syncthreads();
    }
    if (tid == 0) mpart[((size_t)t * NP + p) * 8 + nt] = red[0];
}

// ---------------------------------------------------------------------------
__global__ void k_argmin(const float* __restrict__ mpart, int* __restrict__ idx) {
    int t = blockIdx.x;
    int tid = threadIdx.x;
    __shared__ float m[NP];
    if (tid < NP) {
        float s = 0.f;
        for (int nt = 0; nt < 8; ++nt) s += mpart[((size_t)t * NP + tid) * 8 + nt];
        m[tid] = s;
    }
    __syncthreads();
    if (tid == 0) {
        int best = 0; float bv = m[0];
        for (int p = 1; p < NP; ++p)
            if (m[p] < bv) { bv = m[p]; best = p; }
        idx[t] = best;
    }
}

// ---------------------------------------------------------------------------
// reduce + select: gi[t][j] = bih[j] + sum_kc projpart[sel_p(t)][j][kc]
__global__ void k_gi_reduce(const float* __restrict__ projpart,
                            const float* __restrict__ bih,
                            const int* __restrict__ idx,
                            float* __restrict__ gi) {
    int o = blockIdx.x * 256 + threadIdx.x;
    if (o >= HJ * T_ALL) return;
    int j = o / T_ALL, t = o % T_ALL;
    int p = (t < 11) ? idx[t] : 24;
    const float* src = projpart + ((size_t)p * HJ + j) * 128;
    float s = 0.f;
    for (int kc = 0; kc < 128; ++kc) s += src[kc];
    gi[(size_t)t * HJ + j] = s + bih[j];
}

// ---------------------------------------------------------------------------
__global__ void k_gru(const float* __restrict__ gi, const float* __restrict__ Whh,
                      const float* __restrict__ bhh, int* __restrict__ idx) {
    __shared__ float h[HH], gh[HJ];
    int tid = threadIdx.x;
    if (tid < HH) h[tid] = 0.f;
    __syncthreads();
    for (int t = 0; t < T_ALL; ++t) {
        if (tid < HJ) {
            float s = bhh[tid];
            for (int k = 0; k < HH; ++k) s += Whh[tid * HH + k] * h[k];
            gh[tid] = s;
        }
        __syncthreads();
        if (tid < HH) {
            float gr = gi[t * HJ + tid];
            float gz = gi[t * HJ + 24 + tid];
            float gn = gi[t * HJ + 48 + tid];
            float r = 1.f / (1.f + expf(-(gr + gh[tid])));
            float z = 1.f / (1.f + expf(-(gz + gh[24 + tid])));
            float ng = tanhf(gn + r * gh[48 + tid]);
            h[tid] = (1.f - z) * ng + z * h[tid];
        }
        __syncthreads();
    }
    if (tid == 0) {
        int best = 0; float bv = h[0];
        for (int k = 1; k < HH; ++k)
            if (h[k] > bv) { bv = h[k]; best = k; }
        idx[11] = best;
    }
}

// ---------------------------------------------------------------------------
__global__ void k_gather(const float* __restrict__ G, const int* __restrict__ idx,
                         float4* __restrict__ out) {
    int i = blockIdx.x * 256 + threadIdx.x;
    int t = i >> 18;
    int r = i & 262143;
    const float4* src = (const float4*)(G + (size_t)idx[t] * NN);
    out[i] = src[r];
}

// ---------------------------------------------------------------------------
extern "C" void kernel_launch(void* const* d_in, const int* in_sizes, int n_in,
                              void* d_out, int out_size, void* d_ws, size_t ws_size,
                              hipStream_t stream) {
    const float* inp = (const float*)d_in[0];
    const float* G   = (const float*)d_in[1];
    const float* Wih = (const float*)d_in[2];
    const float* Whh = (const float*)d_in[3];
    const float* bih = (const float*)d_in[4];
    const float* bhh = (const float*)d_in[5];

    float* ws = (float*)d_ws;
    float* sc       = ws + WS_SC;
    float* cov      = ws + WS_COV;
    float* mpart    = ws + WS_MPART;
    int*   idx      = (int*)(ws + WS_IDX);
    float* projpart = ws + WS_PROJ;
    float* gi       = ws + WS_GI;

    char* wsb = (char*)d_ws;
    unsigned short* Ahi = (unsigned short*)(wsb + AB_BASE_BYTES);
    unsigned short* Bhi = (unsigned short*)(wsb + AB_BASE_BYTES + AHI_BYTES);

    bool use_mfma = (ws_size >= WS_NEED_BYTES);

    k_pre1<<<6400, 256, 0, stream>>>(inp, G, sc, Ahi);
    k_pre2<<<608, 256, 0, stream>>>(sc, Bhi, cov);
    if (use_mfma) {
        k_main<<<3264, 256, 0, stream>>>(Ahi, Bhi, sc, Wih, G, cov, mpart, projpart);
    } else {
        k_metrics<<<dim3(8, NP, T1), 256, 0, stream>>>(G, sc, mpart);
        k_gi_proj<<<1152, 256, 0, stream>>>(Wih, G, cov, projpart);
    }
    k_argmin<<<T1, 32, 0, stream>>>(mpart, idx);
    k_gi_reduce<<<4, 256, 0, stream>>>(projpart, bih, idx, gi);
    k_gru<<<1, 128, 0, stream>>>(gi, Whh, bhh, idx);
    k_gather<<<12288, 256, 0, stream>>>(G, idx, (float4*)d_out);
}

// Round 7
// 737.384 us; speedup vs baseline: 1.5955x; 1.5955x over previous
//
#include <hip/hip_runtime.h>
#include <math.h>
#include <stdint.h>

#define N_NODE 1024
#define NC 128            // b*d = 64*2
#define T_ALL 12
#define T1 11
#define NP 24             // period / number of graphs
#define NN (N_NODE*N_NODE)   // 1048576
#define HJ 72             // 3*H
#define HH 24             // H

// ---- workspace layout (float offsets) ----
#define WS_SC     0                                   // 1572864
#define WS_COV    (WS_SC + T_ALL*N_NODE*NC)           // -> 2621440
#define WS_MPART  (WS_COV + NN)                       // -> 2623552
#define WS_IDX    (WS_MPART + T1*NP*8)                // -> 2623568
#define WS_PROJ   (WS_IDX + 16)                       // 12*72*1024 = 884736
#define WS_GI     (WS_PROJ + T_ALL*HJ*1024)           // -> 3509168 (+864)

// byte offsets for fp16 tile arrays (16B aligned)
#define AB_BASE_BYTES ((size_t)(WS_GI + HJ*T_ALL) * 4)   // 14036672
#define AHI_BYTES ((size_t)24*1024*1024*2)            // 50331648 (A fp16)
#define BHI_BYTES ((size_t)11*32*4096*2)              // 2883584 (B fp16)
#define WS_NEED_BYTES (AB_BASE_BYTES + AHI_BYTES + BHI_BYTES)  // ~67.3MB

typedef __attribute__((ext_vector_type(8))) unsigned short ushort8v;
typedef __attribute__((ext_vector_type(8))) _Float16 half8v;
typedef __attribute__((ext_vector_type(4))) float f32x4;

// ---------------------------------------------------------------------------
__device__ __forceinline__ void gload16(const void* g, void* l) {
    __builtin_amdgcn_global_load_lds(
        (const __attribute__((address_space(1))) uint32_t*)g,
        (__attribute__((address_space(3))) uint32_t*)l, 16, 0, 0);
}

__device__ __forceinline__ unsigned short f16_bits(_Float16 h) {
    union { _Float16 f; unsigned short u; } cv; cv.f = h; return cv.u;
}

// ---------------------------------------------------------------------------
// L1 fused: build_sc (256 blocks) + cvt_A (6144 blocks)
__global__ __launch_bounds__(256) void k_pre1(const float* __restrict__ inp,
                                              const float* __restrict__ G,
                                              float* __restrict__ sc,
                                              unsigned short* __restrict__ Ahi) {
    __shared__ float ld[6432];   // addr(n,b,td) = n*201 + b*25 + td
    int tid = threadIdx.x;
    if (blockIdx.x < 256) {
        int b0 = (blockIdx.x & 7) * 8;
        int n0 = (blockIdx.x >> 3) * 32;
        for (int idx = tid; idx < 1536; idx += 256) {
            int bb = idx / 192;
            int rem = idx - bb * 192;
            int nn = rem / 6;
            int q  = rem - nn * 6;
            const float4 v = *(const float4*)(inp +
                ((size_t)(b0 + bb) * 1024 + (n0 + nn)) * 24 + q * 4);
            int base = nn * 201 + bb * 25 + q * 4;
            ld[base + 0] = v.x; ld[base + 1] = v.y;
            ld[base + 2] = v.z; ld[base + 3] = v.w;
        }
        __syncthreads();
        for (int idx = tid; idx < 6144; idx += 256) {
            int t = idx / 512;
            int rem = idx & 511;
            int nn = rem >> 4, cc = rem & 15;
            int bb = cc >> 1, dd = cc & 1;
            sc[(size_t)t * 131072 + (size_t)(n0 + nn) * 128 + b0 * 2 + cc] =
                ld[nn * 201 + bb * 25 + t * 2 + dd];
        }
    } else {
        int tile = blockIdx.x - 256;      // 0..6143 = (p*8+nt)*32+ks
        int ks = tile & 31;
        int pn = tile >> 5;
        int nt = pn & 7, p = pn >> 3;
        const float* Gt = G + (size_t)p * NN + (size_t)(nt * 128) * 1024 + ks * 32;
        size_t base = (size_t)tile * 4096;
#pragma unroll
        for (int g2 = 0; g2 < 2; ++g2) {
            int gid = tid * 2 + g2;   // 0..511
            int r = gid >> 2, gg = gid & 3;
            const float* src = Gt + (size_t)r * 1024 + gg * 8;
            ushort8v h;
#pragma unroll
            for (int j = 0; j < 8; ++j)
                h[j] = f16_bits((_Float16)src[j]);
            int offu = ((r * 64 + gg * 16) ^ ((r & 7) << 4)) >> 1;
            *(ushort8v*)(Ahi + base + offu) = h;
        }
    }
}

// ---------------------------------------------------------------------------
// L2 fused: cvt_B (352 blocks) + cov with inline row-means (256 blocks)
__global__ __launch_bounds__(256) void k_pre2(const float* __restrict__ sc,
                                              unsigned short* __restrict__ Bhi,
                                              float* __restrict__ cov) {
    __shared__ float shbuf[17152];
    __shared__ float meanb[128];
    int tid = threadIdx.x;
    if (blockIdx.x < 352) {
        float (*s)[129] = (float(*)[129])shbuf;
        int tile = blockIdx.x;            // t*32+ks
        int ks = tile & 31;
        int t = tile >> 5;
        const float* S = sc + (size_t)t * (N_NODE * NC) + (size_t)ks * 32 * 128;
#pragma unroll
        for (int i = 0; i < 4; ++i) {
            int fi = tid + i * 256;
            int m = fi >> 5, c4 = fi & 31;
            float4 v = *(const float4*)(S + (size_t)m * 128 + c4 * 4);
            s[m][c4 * 4 + 0] = v.x;
            s[m][c4 * 4 + 1] = v.y;
            s[m][c4 * 4 + 2] = v.z;
            s[m][c4 * 4 + 3] = v.w;
        }
        __syncthreads();
        size_t base = (size_t)tile * 4096;
#pragma unroll
        for (int g2 = 0; g2 < 2; ++g2) {
            int gid = tid * 2 + g2;
            int c = gid >> 2, gg = gid & 3;
            ushort8v h;
#pragma unroll
            for (int j = 0; j < 8; ++j)
                h[j] = f16_bits((_Float16)s[gg * 8 + j][c]);
            int offu = ((c * 64 + gg * 16) ^ ((c & 7) << 4)) >> 1;
            *(ushort8v*)(Bhi + base + offu) = h;
        }
    } else {
        int cb = blockIdx.x - 352;        // 0..255
        int bi = cb >> 4, bj = cb & 15;
        int i0 = bi * 64, j0 = bj * 64;
        float* Ai = shbuf;
        float* Bj = shbuf + 8512;
        const float* L = sc + (size_t)11 * (N_NODE * NC);
#pragma unroll
        for (int it = 0; it < 8; ++it) {
            int fi = tid + it * 256;
            int r = fi >> 5, q = fi & 31;
            float4 a4 = *(const float4*)(L + (size_t)(i0 + r) * 128 + q * 4);
            Ai[r * 133 + q * 4 + 0] = a4.x;
            Ai[r * 133 + q * 4 + 1] = a4.y;
            Ai[r * 133 + q * 4 + 2] = a4.z;
            Ai[r * 133 + q * 4 + 3] = a4.w;
            float4 b4 = *(const float4*)(L + (size_t)(j0 + r) * 128 + q * 4);
            Bj[r * 133 + q * 4 + 0] = b4.x;
            Bj[r * 133 + q * 4 + 1] = b4.y;
            Bj[r * 133 + q * 4 + 2] = b4.z;
            Bj[r * 133 + q * 4 + 3] = b4.w;
        }
        __syncthreads();
        if (tid < 128) {
            int half = tid >> 6, row = tid & 63;
            const float* buf = (half ? Bj : Ai) + row * 133;
            float s = 0.f;
            for (int k = 0; k < 128; ++k) s += buf[k];
            meanb[tid] = s * (1.0f / 128.0f);
        }
        __syncthreads();
#pragma unroll
        for (int it = 0; it < 8; ++it) {
            int fi = tid + it * 256;
            int r = fi >> 5, q = fi & 31;
            float ma = meanb[r], mb = meanb[64 + r];
#pragma unroll
            for (int e = 0; e < 4; ++e) {
                Ai[r * 133 + q * 4 + e] -= ma;
                Bj[r * 133 + q * 4 + e] -= mb;
            }
        }
        __syncthreads();
        int ti = tid >> 4, tj = tid & 15;
        float acc[4][4];
#pragma unroll
        for (int a = 0; a < 4; ++a)
#pragma unroll
            for (int b = 0; b < 4; ++b) acc[a][b] = 0.f;
        for (int k = 0; k < 128; ++k) {
            float a[4], b[4];
#pragma unroll
            for (int rr = 0; rr < 4; ++rr) a[rr] = Ai[(ti * 4 + rr) * 133 + k];
#pragma unroll
            for (int cc = 0; cc < 4; ++cc) b[cc] = Bj[(tj * 4 + cc) * 133 + k];
#pragma unroll
            for (int rr = 0; rr < 4; ++rr)
#pragma unroll
                for (int cc = 0; cc < 4; ++cc)
                    acc[rr][cc] = fmaf(a[rr], b[cc], acc[rr][cc]);
        }
#pragma unroll
        for (int rr = 0; rr < 4; ++rr)
#pragma unroll
            for (int cc = 0; cc < 4; ++cc)
                cov[(size_t)(i0 + ti * 4 + rr) * 1024 + j0 + tj * 4 + cc] =
                    acc[rr][cc] * (1.0f / 127.0f);
    }
}

// ---------------------------------------------------------------------------
// K2 (MFMA): fp16 single-product GEMM + masked abs-diff reduce. (R5-verified)
__global__ __launch_bounds__(256, 4) void k_metrics_mfma(
        const unsigned short* __restrict__ Ahi,
        const unsigned short* __restrict__ Bhi,
        const float* __restrict__ sc, float* __restrict__ mpart) {
    __shared__ unsigned short lds[2][2][4096];   // [img A/B][k-half][8KB tile]
    __shared__ float red[256];

    int bid = blockIdx.x;                      // 0..2111
    int orig = (bid & 7) * 264 + (bid >> 3);   // chunked XCD swizzle (2112 = 8*264)
    int t = orig % 11;
    int pn = orig / 11;                        // 0..191
    int nt = pn & 7, p = pn >> 3;

    int tid = threadIdx.x;
    int lane = tid & 63, wv = tid >> 6;
    int wr = wv >> 1, wc = wv & 1;
    int lr = lane & 15, lg = lane >> 4;

    const unsigned short* srcA = Ahi + (size_t)(p * 8 + nt) * 32 * 4096;
    const unsigned short* srcB = Bhi + (size_t)t * 32 * 4096;

    f32x4 acc[4][4];
#pragma unroll
    for (int m = 0; m < 4; ++m)
#pragma unroll
        for (int n = 0; n < 4; ++n)
            acc[m][n] = (f32x4){0.f, 0.f, 0.f, 0.f};

    int aoff[4], boff[4];
#pragma unroll
    for (int m = 0; m < 4; ++m) {
        int row = wr * 64 + m * 16 + lr;
        aoff[m] = (row * 64 + lg * 16) ^ ((row & 7) << 4);
    }
#pragma unroll
    for (int n = 0; n < 4; ++n) {
        int col = wc * 64 + n * 16 + lr;
        boff[n] = (col * 64 + lg * 16) ^ ((col & 7) << 4);
    }

    const char* LA = (const char*)&lds[0][0][0];
    const char* LB = (const char*)&lds[1][0][0];

    for (int ks2 = 0; ks2 < 16; ++ks2) {
        const unsigned short* sA = srcA + (size_t)ks2 * 8192;
        const unsigned short* sB = srcB + (size_t)ks2 * 8192;
#pragma unroll
        for (int i = 0; i < 8; ++i) {
            int c = wv + i * 4;               // 0..31
            int img = c >> 4, seg = c & 15;
            const unsigned short* sp = (img == 0 ? sA : sB) + seg * 512 + lane * 8;
            gload16(sp, &lds[img][seg >> 3][(seg & 7) * 512]);
        }
        __syncthreads();

        half8v bh[4][2];
#pragma unroll
        for (int n = 0; n < 4; ++n) {
            bh[n][0] = *(const half8v*)(LB + boff[n]);
            bh[n][1] = *(const half8v*)(LB + 8192 + boff[n]);
        }
#pragma unroll
        for (int m = 0; m < 4; ++m) {
            half8v ah0 = *(const half8v*)(LA + aoff[m]);
            half8v ah1 = *(const half8v*)(LA + 8192 + aoff[m]);
#pragma unroll
            for (int n = 0; n < 4; ++n) {
                acc[m][n] = __builtin_amdgcn_mfma_f32_16x16x32_f16(ah0, bh[n][0], acc[m][n], 0, 0, 0);
                acc[m][n] = __builtin_amdgcn_mfma_f32_16x16x32_f16(ah1, bh[n][1], acc[m][n], 0, 0, 0);
            }
        }
        __syncthreads();
    }

    const float* Tg = sc + (size_t)(t + 1) * (N_NODE * NC);
    int n0 = nt * 128;
    float part = 0.f;
#pragma unroll
    for (int m = 0; m < 4; ++m)
#pragma unroll
        for (int j = 0; j < 4; ++j) {
            int row = wr * 64 + m * 16 + lg * 4 + j;
            const float* Trow = Tg + (size_t)(n0 + row) * 128 + wc * 64 + lr;
#pragma unroll
            for (int n = 0; n < 4; ++n) {
                float tg = Trow[n * 16];
                if (tg != 0.0f) part += fabsf(acc[m][n][j] - tg);
            }
        }
    red[tid] = part;
    __syncthreads();
    for (int s = 128; s > 0; s >>= 1) {
        if (tid < s) red[tid] += red[tid + s];
        __syncthreads();
    }
    if (tid == 0) mpart[((size_t)t * NP + p) * 8 + nt] = red[0];
}

// ---------------------------------------------------------------------------
// fp32 metrics fallback (verified round 1) — only if ws_size too small
__global__ __launch_bounds__(256) void k_metrics(const float* __restrict__ G,
                                                 const float* __restrict__ sc,
                                                 float* __restrict__ mpart) {
    __shared__ float As[32 * 132];
    __shared__ float Bs[32 * 132];
    __shared__ float red[256];

    int nt = blockIdx.x, p = blockIdx.y, t = blockIdx.z;
    int tid = threadIdx.x;
    int tr = tid >> 4, tc = tid & 15;
    int n0 = nt * 128;

    const float* Gp = G + (size_t)p * NN + (size_t)n0 * 1024;
    const float* Xt = sc + (size_t)t * (N_NODE * NC);

    float acc[8][8];
#pragma unroll
    for (int a = 0; a < 8; ++a)
#pragma unroll
        for (int b = 0; b < 8; ++b) acc[a][b] = 0.f;

    for (int ko = 0; ko < 1024; ko += 32) {
#pragma unroll
        for (int it = 0; it < 4; ++it) {
            int fi = tid + it * 256;
            int r = fi >> 3, q = fi & 7;
            float4 g4 = *(const float4*)(Gp + (size_t)r * 1024 + ko + q * 4);
            As[(q * 4 + 0) * 132 + r] = g4.x;
            As[(q * 4 + 1) * 132 + r] = g4.y;
            As[(q * 4 + 2) * 132 + r] = g4.z;
            As[(q * 4 + 3) * 132 + r] = g4.w;
        }
#pragma unroll
        for (int it = 0; it < 4; ++it) {
            int fi = tid + it * 256;
            int kk = fi >> 5, cq = fi & 31;
            float4 x4 = *(const float4*)(Xt + (size_t)(ko + kk) * 128 + cq * 4);
            *(float4*)(&Bs[kk * 132 + cq * 4]) = x4;
        }
        __syncthreads();
#pragma unroll
        for (int kk = 0; kk < 32; ++kk) {
            float4 a0 = *(const float4*)(&As[kk * 132 + tr * 8]);
            float4 a1 = *(const float4*)(&As[kk * 132 + tr * 8 + 4]);
            float4 b0 = *(const float4*)(&Bs[kk * 132 + tc * 8]);
            float4 b1 = *(const float4*)(&Bs[kk * 132 + tc * 8 + 4]);
            float a[8] = {a0.x, a0.y, a0.z, a0.w, a1.x, a1.y, a1.z, a1.w};
            float b[8] = {b0.x, b0.y, b0.z, b0.w, b1.x, b1.y, b1.z, b1.w};
#pragma unroll
            for (int rr = 0; rr < 8; ++rr)
#pragma unroll
                for (int cc = 0; cc < 8; ++cc)
                    acc[rr][cc] = fmaf(a[rr], b[cc], acc[rr][cc]);
        }
        __syncthreads();
    }

    const float* Tg = sc + (size_t)(t + 1) * (N_NODE * NC);
    float part = 0.f;
#pragma unroll
    for (int rr = 0; rr < 8; ++rr) {
        int n = n0 + tr * 8 + rr;
#pragma unroll
        for (int cc = 0; cc < 8; ++cc) {
            int c = tc * 8 + cc;
            float tg = Tg[(size_t)n * 128 + c];
            if (tg != 0.0f) part += fabsf(acc[rr][cc] - tg);
        }
    }
    red[tid] = part;
    __syncthreads();
    for (int s = 128; s > 0; s >>= 1) {
        if (tid < s) red[tid] += red[tid + s];
        __syncthreads();
    }
    if (tid == 0) mpart[((size_t)t * NP + p) * 8 + nt] = red[0];
}

// ---------------------------------------------------------------------------
__global__ void k_argmin(const float* __restrict__ mpart, int* __restrict__ idx) {
    int t = blockIdx.x;
    int tid = threadIdx.x;
    __shared__ float m[NP];
    if (tid < NP) {
        float s = 0.f;
        for (int nt = 0; nt < 8; ++nt) s += mpart[((size_t)t * NP + tid) * 8 + nt];
        m[tid] = s;
    }
    __syncthreads();
    if (tid == 0) {
        int best = 0; float bv = m[0];
        for (int p = 1; p < NP; ++p)
            if (m[p] < bv) { bv = m[p]; best = p; }
        idx[t] = best;
    }
}

// ---------------------------------------------------------------------------
// gi projection: stage 12 selected ctx chunks (48KB LDS) ONCE per kc-block,
// stream all 72 W rows against them (j in groups of 3 amortizes LDS reads).
// Traffic: W 302MB + ctx 50MB (each element read exactly once from HBM).
__global__ void k_gi_sel(const float* __restrict__ Wih,
                         const float* __restrict__ G,
                         const float* __restrict__ cov,
                         const int* __restrict__ idx,
                         float* __restrict__ projpart) {
    __shared__ float ctxs[12][1024];   // 48KB
    int kc = blockIdx.x;               // 0..1023 (chunk of 1024 floats)
    int tid = threadIdx.x;
    int lane = tid & 63, wv = tid >> 6;

#pragma unroll
    for (int t = 0; t < 12; ++t) {
        const float* src = (t < 11) ? (G + (size_t)idx[t] * NN) : cov;
        float4 v = *(const float4*)(src + (size_t)kc * 1024 + tid * 4);
        *(float4*)(&ctxs[t][tid * 4]) = v;
    }
    __syncthreads();

    for (int g = 0; g < 6; ++g) {
        int j0 = wv * 18 + g * 3;
        float4 w4[3][4];
#pragma unroll
        for (int jj = 0; jj < 3; ++jj) {
            const float* wrow = Wih + (size_t)(j0 + jj) * NN + (size_t)kc * 1024;
#pragma unroll
            for (int s = 0; s < 4; ++s)
                w4[jj][s] = *(const float4*)(wrow + lane * 4 + s * 256);
        }
        float acc[3][12];
#pragma unroll
        for (int jj = 0; jj < 3; ++jj)
#pragma unroll
            for (int t = 0; t < 12; ++t) acc[jj][t] = 0.f;
#pragma unroll
        for (int t = 0; t < 12; ++t)
#pragma unroll
            for (int s = 0; s < 4; ++s) {
                float4 c4 = *(const float4*)(&ctxs[t][lane * 4 + s * 256]);
#pragma unroll
                for (int jj = 0; jj < 3; ++jj)
                    acc[jj][t] += w4[jj][s].x * c4.x + w4[jj][s].y * c4.y
                                + w4[jj][s].z * c4.z + w4[jj][s].w * c4.w;
            }
#pragma unroll
        for (int jj = 0; jj < 3; ++jj)
#pragma unroll
            for (int t = 0; t < 12; ++t) {
                float v = acc[jj][t];
                for (int off = 32; off > 0; off >>= 1) v += __shfl_xor(v, off);
                if (lane == 0)
                    projpart[((size_t)t * HJ + (j0 + jj)) * 1024 + kc] = v;
            }
    }
}

// wave-per-output reduce: gi[t*72+j] = bih[j] + sum_kc projpart[t*72+j][kc]
__global__ void k_gi_reduce(const float* __restrict__ projpart,
                            const float* __restrict__ bih,
                            float* __restrict__ gi) {
    int o = blockIdx.x * 4 + (threadIdx.x >> 6);   // 0..863
    int lane = threadIdx.x & 63;
    const float* src = projpart + (size_t)o * 1024;
    float s = 0.f;
#pragma unroll
    for (int q = 0; q < 4; ++q) {
        float4 v = *(const float4*)(src + lane * 4 + q * 256);
        s += v.x + v.y + v.z + v.w;
    }
    for (int off = 32; off > 0; off >>= 1) s += __shfl_xor(s, off);
    if (lane == 0) gi[o] = s + bih[o % HJ];
}

// ---------------------------------------------------------------------------
__global__ void k_gru(const float* __restrict__ gi, const float* __restrict__ Whh,
                      const float* __restrict__ bhh, int* __restrict__ idx) {
    __shared__ float h[HH], gh[HJ];
    int tid = threadIdx.x;
    if (tid < HH) h[tid] = 0.f;
    __syncthreads();
    for (int t = 0; t < T_ALL; ++t) {
        if (tid < HJ) {
            float s = bhh[tid];
            for (int k = 0; k < HH; ++k) s += Whh[tid * HH + k] * h[k];
            gh[tid] = s;
        }
        __syncthreads();
        if (tid < HH) {
            float gr = gi[t * HJ + tid];
            float gz = gi[t * HJ + 24 + tid];
            float gn = gi[t * HJ + 48 + tid];
            float r = 1.f / (1.f + expf(-(gr + gh[tid])));
            float z = 1.f / (1.f + expf(-(gz + gh[24 + tid])));
            float ng = tanhf(gn + r * gh[48 + tid]);
            h[tid] = (1.f - z) * ng + z * h[tid];
        }
        __syncthreads();
    }
    if (tid == 0) {
        int best = 0; float bv = h[0];
        for (int k = 1; k < HH; ++k)
            if (h[k] > bv) { bv = h[k]; best = k; }
        idx[11] = best;
    }
}

// ---------------------------------------------------------------------------
__global__ void k_gather(const float* __restrict__ G, const int* __restrict__ idx,
                         float4* __restrict__ out) {
    int i = blockIdx.x * 256 + threadIdx.x;
    int t = i >> 18;
    int r = i & 262143;
    const float4* src = (const float4*)(G + (size_t)idx[t] * NN);
    out[i] = src[r];
}

// ---------------------------------------------------------------------------
extern "C" void kernel_launch(void* const* d_in, const int* in_sizes, int n_in,
                              void* d_out, int out_size, void* d_ws, size_t ws_size,
                              hipStream_t stream) {
    const float* inp = (const float*)d_in[0];
    const float* G   = (const float*)d_in[1];
    const float* Wih = (const float*)d_in[2];
    const float* Whh = (const float*)d_in[3];
    const float* bih = (const float*)d_in[4];
    const float* bhh = (const float*)d_in[5];

    float* ws = (float*)d_ws;
    float* sc       = ws + WS_SC;
    float* cov      = ws + WS_COV;
    float* mpart    = ws + WS_MPART;
    int*   idx      = (int*)(ws + WS_IDX);
    float* projpart = ws + WS_PROJ;
    float* gi       = ws + WS_GI;

    char* wsb = (char*)d_ws;
    unsigned short* Ahi = (unsigned short*)(wsb + AB_BASE_BYTES);
    unsigned short* Bhi = (unsigned short*)(wsb + AB_BASE_BYTES + AHI_BYTES);

    bool use_mfma = (ws_size >= WS_NEED_BYTES);

    k_pre1<<<6400, 256, 0, stream>>>(inp, G, sc, Ahi);
    k_pre2<<<608, 256, 0, stream>>>(sc, Bhi, cov);
    if (use_mfma) {
        k_metrics_mfma<<<2112, 256, 0, stream>>>(Ahi, Bhi, sc, mpart);
    } else {
        k_metrics<<<dim3(8, NP, T1), 256, 0, stream>>>(G, sc, mpart);
    }
    k_argmin<<<T1, 32, 0, stream>>>(mpart, idx);
    k_gi_sel<<<1024, 256, 0, stream>>>(Wih, G, cov, idx, projpart);
    k_gi_reduce<<<216, 256, 0, stream>>>(projpart, bih, gi);
    k_gru<<<1, 128, 0, stream>>>(gi, Whh, bhh, idx);
    k_gather<<<12288, 256, 0, stream>>>(G, idx, (float4*)d_out);
}

// Round 8
// 259.962 us; speedup vs baseline: 4.5257x; 2.8365x over previous
//
#include <hip/hip_runtime.h>
#include <math.h>
#include <stdint.h>

#define N_NODE 1024
#define NC 128            // b*d = 64*2
#define T_ALL 12
#define T1 11
#define NP 24             // period / number of graphs
#define NN (N_NODE*N_NODE)   // 1048576
#define HJ 72             // 3*H
#define HH 24             // H

// ---- workspace layout (float offsets) ----
#define WS_SC     0                                   // 1572864
#define WS_COV    (WS_SC + T_ALL*N_NODE*NC)           // -> 2621440
#define WS_MPART  (WS_COV + NN)                       // -> 2623552
#define WS_IDX    (WS_MPART + T1*NP*8)                // -> 2623568
#define WS_PROJ   (WS_IDX + 16)                       // 12*72*1024 = 884736
#define WS_GI     (WS_PROJ + T_ALL*HJ*1024)           // -> 3509168 (+864)

// byte offsets for fp16 tile arrays (16B aligned)
#define AB_BASE_BYTES ((size_t)(WS_GI + HJ*T_ALL) * 4)   // 14036672
#define AHI_BYTES ((size_t)24*1024*1024*2)            // 50331648 (A fp16)
#define BHI_BYTES ((size_t)11*32*4096*2)              // 2883584 (B fp16)
#define WS_NEED_BYTES (AB_BASE_BYTES + AHI_BYTES + BHI_BYTES)  // ~67.3MB

typedef __attribute__((ext_vector_type(8))) unsigned short ushort8v;
typedef __attribute__((ext_vector_type(8))) _Float16 half8v;
typedef __attribute__((ext_vector_type(4))) float f32x4;

// ---------------------------------------------------------------------------
__device__ __forceinline__ void gload16(const void* g, void* l) {
    __builtin_amdgcn_global_load_lds(
        (const __attribute__((address_space(1))) uint32_t*)g,
        (__attribute__((address_space(3))) uint32_t*)l, 16, 0, 0);
}

__device__ __forceinline__ unsigned short f16_bits(_Float16 h) {
    union { _Float16 f; unsigned short u; } cv; cv.f = h; return cv.u;
}

// ---------------------------------------------------------------------------
// L1 fused: build_sc (256 blocks) + cvt_A (6144 blocks)
__global__ __launch_bounds__(256) void k_pre1(const float* __restrict__ inp,
                                              const float* __restrict__ G,
                                              float* __restrict__ sc,
                                              unsigned short* __restrict__ Ahi) {
    __shared__ float ld[6432];   // addr(n,b,td) = n*201 + b*25 + td
    int tid = threadIdx.x;
    if (blockIdx.x < 256) {
        int b0 = (blockIdx.x & 7) * 8;
        int n0 = (blockIdx.x >> 3) * 32;
        for (int idx = tid; idx < 1536; idx += 256) {
            int bb = idx / 192;
            int rem = idx - bb * 192;
            int nn = rem / 6;
            int q  = rem - nn * 6;
            const float4 v = *(const float4*)(inp +
                ((size_t)(b0 + bb) * 1024 + (n0 + nn)) * 24 + q * 4);
            int base = nn * 201 + bb * 25 + q * 4;
            ld[base + 0] = v.x; ld[base + 1] = v.y;
            ld[base + 2] = v.z; ld[base + 3] = v.w;
        }
        __syncthreads();
        for (int idx = tid; idx < 6144; idx += 256) {
            int t = idx / 512;
            int rem = idx & 511;
            int nn = rem >> 4, cc = rem & 15;
            int bb = cc >> 1, dd = cc & 1;
            sc[(size_t)t * 131072 + (size_t)(n0 + nn) * 128 + b0 * 2 + cc] =
                ld[nn * 201 + bb * 25 + t * 2 + dd];
        }
    } else {
        int tile = blockIdx.x - 256;      // 0..6143 = (p*8+nt)*32+ks
        int ks = tile & 31;
        int pn = tile >> 5;
        int nt = pn & 7, p = pn >> 3;
        const float* Gt = G + (size_t)p * NN + (size_t)(nt * 128) * 1024 + ks * 32;
        size_t base = (size_t)tile * 4096;
#pragma unroll
        for (int g2 = 0; g2 < 2; ++g2) {
            int gid = tid * 2 + g2;   // 0..511
            int r = gid >> 2, gg = gid & 3;
            const float* src = Gt + (size_t)r * 1024 + gg * 8;
            ushort8v h;
#pragma unroll
            for (int j = 0; j < 8; ++j)
                h[j] = f16_bits((_Float16)src[j]);
            int offu = ((r * 64 + gg * 16) ^ ((r & 7) << 4)) >> 1;
            *(ushort8v*)(Ahi + base + offu) = h;
        }
    }
}

// ---------------------------------------------------------------------------
// L2 fused: cvt_B (352 blocks) + cov with inline row-means (256 blocks)
__global__ __launch_bounds__(256) void k_pre2(const float* __restrict__ sc,
                                              unsigned short* __restrict__ Bhi,
                                              float* __restrict__ cov) {
    __shared__ float shbuf[17152];
    __shared__ float meanb[128];
    int tid = threadIdx.x;
    if (blockIdx.x < 352) {
        float (*s)[129] = (float(*)[129])shbuf;
        int tile = blockIdx.x;            // t*32+ks
        int ks = tile & 31;
        int t = tile >> 5;
        const float* S = sc + (size_t)t * (N_NODE * NC) + (size_t)ks * 32 * 128;
#pragma unroll
        for (int i = 0; i < 4; ++i) {
            int fi = tid + i * 256;
            int m = fi >> 5, c4 = fi & 31;
            float4 v = *(const float4*)(S + (size_t)m * 128 + c4 * 4);
            s[m][c4 * 4 + 0] = v.x;
            s[m][c4 * 4 + 1] = v.y;
            s[m][c4 * 4 + 2] = v.z;
            s[m][c4 * 4 + 3] = v.w;
        }
        __syncthreads();
        size_t base = (size_t)tile * 4096;
#pragma unroll
        for (int g2 = 0; g2 < 2; ++g2) {
            int gid = tid * 2 + g2;
            int c = gid >> 2, gg = gid & 3;
            ushort8v h;
#pragma unroll
            for (int j = 0; j < 8; ++j)
                h[j] = f16_bits((_Float16)s[gg * 8 + j][c]);
            int offu = ((c * 64 + gg * 16) ^ ((c & 7) << 4)) >> 1;
            *(ushort8v*)(Bhi + base + offu) = h;
        }
    } else {
        int cb = blockIdx.x - 352;        // 0..255
        int bi = cb >> 4, bj = cb & 15;
        int i0 = bi * 64, j0 = bj * 64;
        float* Ai = shbuf;
        float* Bj = shbuf + 8512;
        const float* L = sc + (size_t)11 * (N_NODE * NC);
#pragma unroll
        for (int it = 0; it < 8; ++it) {
            int fi = tid + it * 256;
            int r = fi >> 5, q = fi & 31;
            float4 a4 = *(const float4*)(L + (size_t)(i0 + r) * 128 + q * 4);
            Ai[r * 133 + q * 4 + 0] = a4.x;
            Ai[r * 133 + q * 4 + 1] = a4.y;
            Ai[r * 133 + q * 4 + 2] = a4.z;
            Ai[r * 133 + q * 4 + 3] = a4.w;
            float4 b4 = *(const float4*)(L + (size_t)(j0 + r) * 128 + q * 4);
            Bj[r * 133 + q * 4 + 0] = b4.x;
            Bj[r * 133 + q * 4 + 1] = b4.y;
            Bj[r * 133 + q * 4 + 2] = b4.z;
            Bj[r * 133 + q * 4 + 3] = b4.w;
        }
        __syncthreads();
        if (tid < 128) {
            int half = tid >> 6, row = tid & 63;
            const float* buf = (half ? Bj : Ai) + row * 133;
            float s = 0.f;
            for (int k = 0; k < 128; ++k) s += buf[k];
            meanb[tid] = s * (1.0f / 128.0f);
        }
        __syncthreads();
#pragma unroll
        for (int it = 0; it < 8; ++it) {
            int fi = tid + it * 256;
            int r = fi >> 5, q = fi & 31;
            float ma = meanb[r], mb = meanb[64 + r];
#pragma unroll
            for (int e = 0; e < 4; ++e) {
                Ai[r * 133 + q * 4 + e] -= ma;
                Bj[r * 133 + q * 4 + e] -= mb;
            }
        }
        __syncthreads();
        int ti = tid >> 4, tj = tid & 15;
        float acc[4][4];
#pragma unroll
        for (int a = 0; a < 4; ++a)
#pragma unroll
            for (int b = 0; b < 4; ++b) acc[a][b] = 0.f;
        for (int k = 0; k < 128; ++k) {
            float a[4], b[4];
#pragma unroll
            for (int rr = 0; rr < 4; ++rr) a[rr] = Ai[(ti * 4 + rr) * 133 + k];
#pragma unroll
            for (int cc = 0; cc < 4; ++cc) b[cc] = Bj[(tj * 4 + cc) * 133 + k];
#pragma unroll
            for (int rr = 0; rr < 4; ++rr)
#pragma unroll
                for (int cc = 0; cc < 4; ++cc)
                    acc[rr][cc] = fmaf(a[rr], b[cc], acc[rr][cc]);
        }
#pragma unroll
        for (int rr = 0; rr < 4; ++rr)
#pragma unroll
            for (int cc = 0; cc < 4; ++cc)
                cov[(size_t)(i0 + ti * 4 + rr) * 1024 + j0 + tj * 4 + cc] =
                    acc[rr][cc] * (1.0f / 127.0f);
    }
}

// ---------------------------------------------------------------------------
// K2 (MFMA): fp16 single-product GEMM + masked abs-diff reduce. (R5-verified)
__global__ __launch_bounds__(256, 4) void k_metrics_mfma(
        const unsigned short* __restrict__ Ahi,
        const unsigned short* __restrict__ Bhi,
        const float* __restrict__ sc, float* __restrict__ mpart) {
    __shared__ unsigned short lds[2][2][4096];   // [img A/B][k-half][8KB tile]
    __shared__ float red[256];

    int bid = blockIdx.x;                      // 0..2111
    int orig = (bid & 7) * 264 + (bid >> 3);   // chunked XCD swizzle (2112 = 8*264)
    int t = orig % 11;
    int pn = orig / 11;                        // 0..191
    int nt = pn & 7, p = pn >> 3;

    int tid = threadIdx.x;
    int lane = tid & 63, wv = tid >> 6;
    int wr = wv >> 1, wc = wv & 1;
    int lr = lane & 15, lg = lane >> 4;

    const unsigned short* srcA = Ahi + (size_t)(p * 8 + nt) * 32 * 4096;
    const unsigned short* srcB = Bhi + (size_t)t * 32 * 4096;

    f32x4 acc[4][4];
#pragma unroll
    for (int m = 0; m < 4; ++m)
#pragma unroll
        for (int n = 0; n < 4; ++n)
            acc[m][n] = (f32x4){0.f, 0.f, 0.f, 0.f};

    int aoff[4], boff[4];
#pragma unroll
    for (int m = 0; m < 4; ++m) {
        int row = wr * 64 + m * 16 + lr;
        aoff[m] = (row * 64 + lg * 16) ^ ((row & 7) << 4);
    }
#pragma unroll
    for (int n = 0; n < 4; ++n) {
        int col = wc * 64 + n * 16 + lr;
        boff[n] = (col * 64 + lg * 16) ^ ((col & 7) << 4);
    }

    const char* LA = (const char*)&lds[0][0][0];
    const char* LB = (const char*)&lds[1][0][0];

    for (int ks2 = 0; ks2 < 16; ++ks2) {
        const unsigned short* sA = srcA + (size_t)ks2 * 8192;
        const unsigned short* sB = srcB + (size_t)ks2 * 8192;
#pragma unroll
        for (int i = 0; i < 8; ++i) {
            int c = wv + i * 4;               // 0..31
            int img = c >> 4, seg = c & 15;
            const unsigned short* sp = (img == 0 ? sA : sB) + seg * 512 + lane * 8;
            gload16(sp, &lds[img][seg >> 3][(seg & 7) * 512]);
        }
        __syncthreads();

        half8v bh[4][2];
#pragma unroll
        for (int n = 0; n < 4; ++n) {
            bh[n][0] = *(const half8v*)(LB + boff[n]);
            bh[n][1] = *(const half8v*)(LB + 8192 + boff[n]);
        }
#pragma unroll
        for (int m = 0; m < 4; ++m) {
            half8v ah0 = *(const half8v*)(LA + aoff[m]);
            half8v ah1 = *(const half8v*)(LA + 8192 + aoff[m]);
#pragma unroll
            for (int n = 0; n < 4; ++n) {
                acc[m][n] = __builtin_amdgcn_mfma_f32_16x16x32_f16(ah0, bh[n][0], acc[m][n], 0, 0, 0);
                acc[m][n] = __builtin_amdgcn_mfma_f32_16x16x32_f16(ah1, bh[n][1], acc[m][n], 0, 0, 0);
            }
        }
        __syncthreads();
    }

    const float* Tg = sc + (size_t)(t + 1) * (N_NODE * NC);
    int n0 = nt * 128;
    float part = 0.f;
#pragma unroll
    for (int m = 0; m < 4; ++m)
#pragma unroll
        for (int j = 0; j < 4; ++j) {
            int row = wr * 64 + m * 16 + lg * 4 + j;
            const float* Trow = Tg + (size_t)(n0 + row) * 128 + wc * 64 + lr;
#pragma unroll
            for (int n = 0; n < 4; ++n) {
                float tg = Trow[n * 16];
                if (tg != 0.0f) part += fabsf(acc[m][n][j] - tg);
            }
        }
    red[tid] = part;
    __syncthreads();
    for (int s = 128; s > 0; s >>= 1) {
        if (tid < s) red[tid] += red[tid + s];
        __syncthreads();
    }
    if (tid == 0) mpart[((size_t)t * NP + p) * 8 + nt] = red[0];
}

// ---------------------------------------------------------------------------
// fp32 metrics fallback (verified round 1) — only if ws_size too small
__global__ __launch_bounds__(256) void k_metrics(const float* __restrict__ G,
                                                 const float* __restrict__ sc,
                                                 float* __restrict__ mpart) {
    __shared__ float As[32 * 132];
    __shared__ float Bs[32 * 132];
    __shared__ float red[256];

    int nt = blockIdx.x, p = blockIdx.y, t = blockIdx.z;
    int tid = threadIdx.x;
    int tr = tid >> 4, tc = tid & 15;
    int n0 = nt * 128;

    const float* Gp = G + (size_t)p * NN + (size_t)n0 * 1024;
    const float* Xt = sc + (size_t)t * (N_NODE * NC);

    float acc[8][8];
#pragma unroll
    for (int a = 0; a < 8; ++a)
#pragma unroll
        for (int b = 0; b < 8; ++b) acc[a][b] = 0.f;

    for (int ko = 0; ko < 1024; ko += 32) {
#pragma unroll
        for (int it = 0; it < 4; ++it) {
            int fi = tid + it * 256;
            int r = fi >> 3, q = fi & 7;
            float4 g4 = *(const float4*)(Gp + (size_t)r * 1024 + ko + q * 4);
            As[(q * 4 + 0) * 132 + r] = g4.x;
            As[(q * 4 + 1) * 132 + r] = g4.y;
            As[(q * 4 + 2) * 132 + r] = g4.z;
            As[(q * 4 + 3) * 132 + r] = g4.w;
        }
#pragma unroll
        for (int it = 0; it < 4; ++it) {
            int fi = tid + it * 256;
            int kk = fi >> 5, cq = fi & 31;
            float4 x4 = *(const float4*)(Xt + (size_t)(ko + kk) * 128 + cq * 4);
            *(float4*)(&Bs[kk * 132 + cq * 4]) = x4;
        }
        __syncthreads();
#pragma unroll
        for (int kk = 0; kk < 32; ++kk) {
            float4 a0 = *(const float4*)(&As[kk * 132 + tr * 8]);
            float4 a1 = *(const float4*)(&As[kk * 132 + tr * 8 + 4]);
            float4 b0 = *(const float4*)(&Bs[kk * 132 + tc * 8]);
            float4 b1 = *(const float4*)(&Bs[kk * 132 + tc * 8 + 4]);
            float a[8] = {a0.x, a0.y, a0.z, a0.w, a1.x, a1.y, a1.z, a1.w};
            float b[8] = {b0.x, b0.y, b0.z, b0.w, b1.x, b1.y, b1.z, b1.w};
#pragma unroll
            for (int rr = 0; rr < 8; ++rr)
#pragma unroll
                for (int cc = 0; cc < 8; ++cc)
                    acc[rr][cc] = fmaf(a[rr], b[cc], acc[rr][cc]);
        }
        __syncthreads();
    }

    const float* Tg = sc + (size_t)(t + 1) * (N_NODE * NC);
    float part = 0.f;
#pragma unroll
    for (int rr = 0; rr < 8; ++rr) {
        int n = n0 + tr * 8 + rr;
#pragma unroll
        for (int cc = 0; cc < 8; ++cc) {
            int c = tc * 8 + cc;
            float tg = Tg[(size_t)n * 128 + c];
            if (tg != 0.0f) part += fabsf(acc[rr][cc] - tg);
        }
    }
    red[tid] = part;
    __syncthreads();
    for (int s = 128; s > 0; s >>= 1) {
        if (tid < s) red[tid] += red[tid + s];
        __syncthreads();
    }
    if (tid == 0) mpart[((size_t)t * NP + p) * 8 + nt] = red[0];
}

// ---------------------------------------------------------------------------
__global__ void k_argmin(const float* __restrict__ mpart, int* __restrict__ idx) {
    int t = blockIdx.x;
    int tid = threadIdx.x;
    __shared__ float m[NP];
    if (tid < NP) {
        float s = 0.f;
        for (int nt = 0; nt < 8; ++nt) s += mpart[((size_t)t * NP + tid) * 8 + nt];
        m[tid] = s;
    }
    __syncthreads();
    if (tid == 0) {
        int best = 0; float bv = m[0];
        for (int p = 1; p < NP; ++p)
            if (m[p] < bv) { bv = m[p]; best = p; }
        idx[t] = best;
    }
}

// ---------------------------------------------------------------------------
// gi projection: stage 12 selected ctx chunks (48KB LDS) ONCE per kc-block,
// stream all 72 W rows against them in j-PAIRS (w4[2][4]=32 + acc[2][12]=24
// regs, statically indexed; launch_bounds(256) so VGPR budget is 102+, no
// spill — R7's 64-VGPR/spill failure was the missing launch_bounds).
__global__ __launch_bounds__(256) void k_gi_sel(const float* __restrict__ Wih,
                                                const float* __restrict__ G,
                                                const float* __restrict__ cov,
                                                const int* __restrict__ idx,
                                                float* __restrict__ projpart) {
    __shared__ float ctxs[12][1024];   // 48KB
    int kc = blockIdx.x;               // 0..1023 (chunk of 1024 floats)
    int tid = threadIdx.x;
    int lane = tid & 63, wv = tid >> 6;

#pragma unroll
    for (int t = 0; t < 12; ++t) {
        const float* src = (t < 11) ? (G + (size_t)idx[t] * NN) : cov;
        float4 v = *(const float4*)(src + (size_t)kc * 1024 + tid * 4);
        *(float4*)(&ctxs[t][tid * 4]) = v;
    }
    __syncthreads();

    for (int g = 0; g < 9; ++g) {
        int j0 = wv * 18 + g * 2;
        float4 w4a[4], w4b[4];
        const float* wra = Wih + (size_t)j0 * NN + (size_t)kc * 1024;
        const float* wrb = wra + NN;
#pragma unroll
        for (int s = 0; s < 4; ++s) {
            w4a[s] = *(const float4*)(wra + lane * 4 + s * 256);
            w4b[s] = *(const float4*)(wrb + lane * 4 + s * 256);
        }
        float acca[12], accb[12];
#pragma unroll
        for (int t = 0; t < 12; ++t) { acca[t] = 0.f; accb[t] = 0.f; }
#pragma unroll
        for (int t = 0; t < 12; ++t)
#pragma unroll
            for (int s = 0; s < 4; ++s) {
                float4 c4 = *(const float4*)(&ctxs[t][lane * 4 + s * 256]);
                acca[t] += w4a[s].x * c4.x + w4a[s].y * c4.y
                         + w4a[s].z * c4.z + w4a[s].w * c4.w;
                accb[t] += w4b[s].x * c4.x + w4b[s].y * c4.y
                         + w4b[s].z * c4.z + w4b[s].w * c4.w;
            }
#pragma unroll
        for (int t = 0; t < 12; ++t) {
            float va = acca[t], vb = accb[t];
            for (int off = 32; off > 0; off >>= 1) {
                va += __shfl_xor(va, off);
                vb += __shfl_xor(vb, off);
            }
            if (lane == 0) {
                projpart[((size_t)t * HJ + j0) * 1024 + kc] = va;
                projpart[((size_t)t * HJ + j0 + 1) * 1024 + kc] = vb;
            }
        }
    }
}

// wave-per-output reduce: gi[t*72+j] = bih[j] + sum_kc projpart[t*72+j][kc]
__global__ __launch_bounds__(256) void k_gi_reduce(const float* __restrict__ projpart,
                                                   const float* __restrict__ bih,
                                                   float* __restrict__ gi) {
    int o = blockIdx.x * 4 + (threadIdx.x >> 6);   // 0..863
    int lane = threadIdx.x & 63;
    const float* src = projpart + (size_t)o * 1024;
    float s = 0.f;
#pragma unroll
    for (int q = 0; q < 4; ++q) {
        float4 v = *(const float4*)(src + lane * 4 + q * 256);
        s += v.x + v.y + v.z + v.w;
    }
    for (int off = 32; off > 0; off >>= 1) s += __shfl_xor(s, off);
    if (lane == 0) gi[o] = s + bih[o % HJ];
}

// ---------------------------------------------------------------------------
__global__ void k_gru(const float* __restrict__ gi, const float* __restrict__ Whh,
                      const float* __restrict__ bhh, int* __restrict__ idx) {
    __shared__ float h[HH], gh[HJ];
    int tid = threadIdx.x;
    if (tid < HH) h[tid] = 0.f;
    __syncthreads();
    for (int t = 0; t < T_ALL; ++t) {
        if (tid < HJ) {
            float s = bhh[tid];
            for (int k = 0; k < HH; ++k) s += Whh[tid * HH + k] * h[k];
            gh[tid] = s;
        }
        __syncthreads();
        if (tid < HH) {
            float gr = gi[t * HJ + tid];
            float gz = gi[t * HJ + 24 + tid];
            float gn = gi[t * HJ + 48 + tid];
            float r = 1.f / (1.f + expf(-(gr + gh[tid])));
            float z = 1.f / (1.f + expf(-(gz + gh[24 + tid])));
            float ng = tanhf(gn + r * gh[48 + tid]);
            h[tid] = (1.f - z) * ng + z * h[tid];
        }
        __syncthreads();
    }
    if (tid == 0) {
        int best = 0; float bv = h[0];
        for (int k = 1; k < HH; ++k)
            if (h[k] > bv) { bv = h[k]; best = k; }
        idx[11] = best;
    }
}

// ---------------------------------------------------------------------------
__global__ void k_gather(const float* __restrict__ G, const int* __restrict__ idx,
                         float4* __restrict__ out) {
    int i = blockIdx.x * 256 + threadIdx.x;
    int t = i >> 18;
    int r = i & 262143;
    const float4* src = (const float4*)(G + (size_t)idx[t] * NN);
    out[i] = src[r];
}

// ---------------------------------------------------------------------------
extern "C" void kernel_launch(void* const* d_in, const int* in_sizes, int n_in,
                              void* d_out, int out_size, void* d_ws, size_t ws_size,
                              hipStream_t stream) {
    const float* inp = (const float*)d_in[0];
    const float* G   = (const float*)d_in[1];
    const float* Wih = (const float*)d_in[2];
    const float* Whh = (const float*)d_in[3];
    const float* bih = (const float*)d_in[4];
    const float* bhh = (const float*)d_in[5];

    float* ws = (float*)d_ws;
    float* sc       = ws + WS_SC;
    float* cov      = ws + WS_COV;
    float* mpart    = ws + WS_MPART;
    int*   idx      = (int*)(ws + WS_IDX);
    float* projpart = ws + WS_PROJ;
    float* gi       = ws + WS_GI;

    char* wsb = (char*)d_ws;
    unsigned short* Ahi = (unsigned short*)(wsb + AB_BASE_BYTES);
    unsigned short* Bhi = (unsigned short*)(wsb + AB_BASE_BYTES + AHI_BYTES);

    bool use_mfma = (ws_size >= WS_NEED_BYTES);

    k_pre1<<<6400, 256, 0, stream>>>(inp, G, sc, Ahi);
    k_pre2<<<608, 256, 0, stream>>>(sc, Bhi, cov);
    if (use_mfma) {
        k_metrics_mfma<<<2112, 256, 0, stream>>>(Ahi, Bhi, sc, mpart);
    } else {
        k_metrics<<<dim3(8, NP, T1), 256, 0, stream>>>(G, sc, mpart);
    }
    k_argmin<<<T1, 32, 0, stream>>>(mpart, idx);
    k_gi_sel<<<1024, 256, 0, stream>>>(Wih, G, cov, idx, projpart);
    k_gi_reduce<<<216, 256, 0, stream>>>(projpart, bih, gi);
    k_gru<<<1, 128, 0, stream>>>(gi, Whh, bhh, idx);
    k_gather<<<12288, 256, 0, stream>>>(G, idx, (float4*)d_out);
}